// Round 8
// baseline (361.048 us; speedup 1.0000x reference)
//
#include <hip/hip_runtime.h>
#include <math.h>

// Fused CNN classifier: conv(1->8,3x3,s2,p1)+ReLU -> conv(8->16,3x3,s2,p1)+ReLU
//                       -> FC(784->1) -> softplus+0.001 -> 1-exp(-r) -> clip
// B=65536 images of 1x28x28 fp32.
//
// R8 (2nd resubmit — R6/R7 benches were GPUAcquisitionTimeouts, no data):
// kill scratch traffic. R7's counters showed WRITE_SIZE 0.5->170 MB with
// no new global stores = private-segment (scratch) traffic; VGPR stuck at 52
// with ~100 live values. Prime suspect: the type-punning union in the conv1
// pack (written as 4xu32, read as bf16x8) defeats SROA -> stack-allocated ->
// 4 scratch stores + 1 scratch reload per i-iter per lane, ON the conv1
// serial chain. Fix: four SSA scalars pk0..pk3 (same v_cvt_pk_bf16_f32),
// assembled into a uint4 and stored directly to LDS (bit-identical 16 B).
// Everything else unchanged from R7 (barrier-free, wave-private LDS, reg
// prefetch, hoisted addressing).
// Predicted: WRITE_SIZE -> ~1 MB, VGPR rises, dur 160 -> 120-140 if scratch
// round-trips were on the chain.

typedef short bf16x8 __attribute__((ext_vector_type(8)));
typedef float f32x4  __attribute__((ext_vector_type(4)));

#define NBLOCKS 4096
#define Z1_RS 19                    // z1 row stride in 16B slots (odd!)
#define Z1_SLOTS (15 * Z1_RS)       // 285 slots per image
#define IMG_RS 36                   // simg row stride in floats (16B-aligned rows)
#define IMG_ROWS 29                 // rows -1..27 stored at ro = r+1
#define IMG_FLOATS (IMG_ROWS * IMG_RS)   // 1044 floats = 4176 B

static __device__ __forceinline__ short f2bf(float f) {
    union { float f; unsigned u; } v; v.f = f;
    unsigned r = v.u + 0x7FFF + ((v.u >> 16) & 1);   // RNE (no NaN inputs)
    return (short)(r >> 16);
}

// One conv1 channel pair (CA, CA+1): 9-tap FMA + ReLU + pack to 2xbf16.
#define CONV1_PAIR(CA, PKDST) do {                                          \
    const float* wa_ = &W1[(CA) * 9];                                       \
    const float* wc_ = &W1[((CA) + 1) * 9];                                 \
    float za_ = b1[(CA)], zc_ = b1[(CA) + 1];                               \
    za_ = fmaf(t0, wa_[0], za_); zc_ = fmaf(t0, wc_[0], zc_);               \
    za_ = fmaf(t1, wa_[1], za_); zc_ = fmaf(t1, wc_[1], zc_);               \
    za_ = fmaf(t2, wa_[2], za_); zc_ = fmaf(t2, wc_[2], zc_);               \
    za_ = fmaf(t3, wa_[3], za_); zc_ = fmaf(t3, wc_[3], zc_);               \
    za_ = fmaf(t4, wa_[4], za_); zc_ = fmaf(t4, wc_[4], zc_);               \
    za_ = fmaf(t5, wa_[5], za_); zc_ = fmaf(t5, wc_[5], zc_);               \
    za_ = fmaf(t6, wa_[6], za_); zc_ = fmaf(t6, wc_[6], zc_);               \
    za_ = fmaf(t7, wa_[7], za_); zc_ = fmaf(t7, wc_[7], zc_);               \
    za_ = fmaf(t8, wa_[8], za_); zc_ = fmaf(t8, wc_[8], zc_);               \
    za_ = fmaxf(za_, 0.f);       zc_ = fmaxf(zc_, 0.f);                     \
    asm("v_cvt_pk_bf16_f32 %0, %1, %2" : "=v"(PKDST) : "v"(za_), "v"(zc_)); \
} while (0)

__global__ __launch_bounds__(256, 4) void fused_cnn_mfma(
    const float* __restrict__ x,
    const float* __restrict__ W1, const float* __restrict__ b1,
    const float* __restrict__ W2, const float* __restrict__ b2,
    const float* __restrict__ Wfc, const float* __restrict__ bfc,
    float* __restrict__ out, int nimg)
{
    __shared__ __align__(16) float simg[4][IMG_FLOATS];   // 16704 B
    __shared__ bf16x8 sz1[4][Z1_SLOTS];                   // 18240 B

    const int tid  = threadIdx.x;
    const int w    = tid >> 6;       // wave id = image slot (wave-private LDS)
    const int lane = tid & 63;
    const int hi   = lane >> 4;
    const int lo   = lane & 15;

    // ---------------- one-time setup (all wave-private, no barrier) --------
    {
        f32x4 z4 = {0.f, 0.f, 0.f, 0.f};
        f32x4* sp = (f32x4*)&simg[w][0];
        for (int i = lane; i < IMG_FLOATS / 4; i += 64) sp[i] = z4;
        bf16x8 zz = {0,0,0,0,0,0,0,0};
        for (int i = lane; i < Z1_SLOTS; i += 64) sz1[w][i] = zz;
    }

    // B-frags: W2 as bf16 in registers. k = tap*8 + ic; lane(hi,lo):
    // B[k=kk*32+hi*8+j][n=lo] -> tap = kk*4+hi, ic=j. tap>=9 => 0 (K-pad).
    bf16x8 wb[3];
    #pragma unroll
    for (int kk = 0; kk < 3; kk++) {
        const int tap = kk * 4 + hi;
        #pragma unroll
        for (int j = 0; j < 8; j++)
            wb[kk][j] = (tap < 9) ? f2bf(W2[lo * 72 + j * 9 + tap])
                                  : (short)0;
    }

    // conv2 A-read byte offsets into sz1[w]: slot = (2qy+ty)*19 + (2qx+tx)
    int posoff[4];
    #pragma unroll
    for (int t = 0; t < 4; t++) {
        int p = t * 16 + lo; if (p > 48) p = 48;
        int qy = p / 7, qx = p - qy * 7;
        posoff[t] = ((2 * qy) * Z1_RS + 2 * qx) * 16;
    }
    int tapoff[3];
    #pragma unroll
    for (int kk = 0; kk < 3; kk++) {
        int tap = kk * 4 + hi;
        int ty = tap / 3, tx = tap - ty * 3;
        tapoff[kk] = (tap < 9) ? (ty * Z1_RS + tx) * 16 : 0;
    }

    // Staging constants: per j, float4 index in image + dst float offset.
    int src4[4], dstf[4];
    #pragma unroll
    for (int j = 0; j < 4; j++) {
        int p4 = j * 64 + lane; if (p4 > 195) p4 = 195;
        int yy = p4 / 7, xq = p4 - yy * 7;
        src4[j] = p4;
        dstf[j] = (yy + 1) * IMG_RS + 4 + 4 * xq;   // 16B-aligned
    }

    // conv1 constants: per i, read base offset + z1 write byte offset.
    int wboff[4], zoff[4];
    #pragma unroll
    for (int i = 0; i < 4; i++) {
        int p = i * 64 + lane; if (p > 195) p = 195;
        int py = p / 14, px = p - py * 14;
        wboff[i] = (2 * py) * IMG_RS + 2 * px + 3;
        zoff[i]  = ((py + 1) * Z1_RS + px + 1) * 16;
    }

    // Epilogue constants: lane(hi,lo) holds D[pos=t*16+hi*4+r][c2=lo].
    const float b2v = b2[lo];
    float wfc[4][4];
    #pragma unroll
    for (int t = 0; t < 4; t++)
        #pragma unroll
        for (int r = 0; r < 4; r++) {
            int p = t * 16 + hi * 4 + r;
            wfc[t][r] = (p < 49) ? Wfc[lo * 49 + p] : 0.f;
        }
    const float bfc0 = bfc[0];

    const int nquad = (nimg + 3) >> 2;
    float* const sw = &simg[w][0];
    char* const z1b = (char*)&sz1[w][0];

    // ---- prologue prefetch: image for q = blockIdx.x ----
    float4 pf[4];
    {
        int img = blockIdx.x * 4 + w;
        if (img >= nimg) img = nimg - 1;
        const float4* sp = (const float4*)(x + (size_t)img * 784);
        #pragma unroll
        for (int j = 0; j < 4; j++) pf[j] = sp[src4[j]];
    }

    for (int q = blockIdx.x; q < nquad; q += gridDim.x) {
        // ---- write prefetched image to LDS (wave-private, aligned b128) ----
        *(float4*)(sw + dstf[0]) = pf[0];
        *(float4*)(sw + dstf[1]) = pf[1];
        *(float4*)(sw + dstf[2]) = pf[2];
        if (lane < 4) *(float4*)(sw + dstf[3]) = pf[3];

        // ---- issue next image's loads; they complete under conv1+conv2 ----
        {
            int qn = q + gridDim.x;
            if (qn < nquad) {
                int imgn = qn * 4 + w;
                if (imgn >= nimg) imgn = nimg - 1;
                const float4* sp = (const float4*)(x + (size_t)imgn * 784);
                #pragma unroll
                for (int j = 0; j < 4; j++) pf[j] = sp[src4[j]];
            }
        }

        // ---- conv1 (fp32 VALU); pack via v_cvt_pk_bf16_f32 into SSA regs ----
        #pragma unroll
        for (int i = 0; i < 4; i++) {
            const float* wbse = sw + wboff[i];
            float t0 = wbse[0],            t1 = wbse[1],              t2 = wbse[2];
            float t3 = wbse[IMG_RS],       t4 = wbse[IMG_RS + 1],     t5 = wbse[IMG_RS + 2];
            float t6 = wbse[2 * IMG_RS],   t7 = wbse[2 * IMG_RS + 1], t8 = wbse[2 * IMG_RS + 2];
            asm volatile("" : "+v"(t0), "+v"(t1), "+v"(t2), "+v"(t3), "+v"(t4),
                              "+v"(t5), "+v"(t6), "+v"(t7), "+v"(t8));
            unsigned pk0, pk1, pk2, pk3;
            CONV1_PAIR(0, pk0);
            CONV1_PAIR(2, pk1);
            CONV1_PAIR(4, pk2);
            CONV1_PAIR(6, pk3);
            uint4 zz; zz.x = pk0; zz.y = pk1; zz.z = pk2; zz.w = pk3;
            if (i < 3 || lane < 4) *(uint4*)(z1b + zoff[i]) = zz;
        }

        // ---- conv2: 4 pos-tiles x 3 K-steps; A = z1 (one b128/frag) ----
        f32x4 acc[4];
        {
            f32x4 z4 = {0.f, 0.f, 0.f, 0.f};
            #pragma unroll
            for (int t = 0; t < 4; t++) acc[t] = z4;
        }
        #pragma unroll
        for (int t = 0; t < 4; t++) {
            #pragma unroll
            for (int kk = 0; kk < 3; kk++) {
                bf16x8 af = *(const bf16x8*)(z1b + posoff[t] + tapoff[kk]);
                acc[t] = __builtin_amdgcn_mfma_f32_16x16x32_bf16(
                             af, wb[kk], acc[t], 0, 0, 0);
            }
        }

        // ---- epilogue: bias+ReLU+FC fold, wave reduce, softplus ----
        float fc = 0.f;
        #pragma unroll
        for (int t = 0; t < 4; t++)
            #pragma unroll
            for (int r = 0; r < 4; r++) {
                float z = fmaxf(acc[t][r] + b2v, 0.f);
                fc = fmaf(z, wfc[t][r], fc);
            }
        #pragma unroll
        for (int off = 32; off > 0; off >>= 1)
            fc += __shfl_down(fc, off, 64);

        if (lane == 0) {
            int img = q * 4 + w;
            if (img < nimg) {
                float v    = fc + bfc0;
                float sp   = fmaxf(v, 0.f) + log1pf(expf(-fabsf(v)));
                float rate = sp + 0.001f;
                float pr   = 1.f - expf(-rate);
                out[img] = fminf(fmaxf(pr, 1e-6f), 1.f - 1e-6f);
            }
        }
    }
}

extern "C" void kernel_launch(void* const* d_in, const int* in_sizes, int n_in,
                              void* d_out, int out_size, void* d_ws, size_t ws_size,
                              hipStream_t stream) {
    const float* x   = (const float*)d_in[0];
    const float* W1  = (const float*)d_in[1];
    const float* b1  = (const float*)d_in[2];
    const float* W2  = (const float*)d_in[3];
    const float* b2  = (const float*)d_in[4];
    const float* Wfc = (const float*)d_in[5];
    const float* bfc = (const float*)d_in[6];
    float* out = (float*)d_out;

    const int nimg  = in_sizes[0] / 784;
    const int nquad = (nimg + 3) / 4;
    const int grid  = nquad < NBLOCKS ? nquad : NBLOCKS;

    fused_cnn_mfma<<<grid, 256, 0, stream>>>(x, W1, b1, W2, b2, Wfc, bfc,
                                             out, nimg);
}

// Round 9
// 316.507 us; speedup vs baseline: 1.1407x; 1.1407x over previous
//
#include <hip/hip_runtime.h>
#include <math.h>

// Fused CNN classifier: conv(1->8,3x3,s2,p1)+ReLU -> conv(8->16,3x3,s2,p1)+ReLU
//                       -> FC(784->1) -> softplus+0.001 -> 1-exp(-r) -> clip
// B=65536 images of 1x28x28 fp32.
//
// R9: SSA-ify ALL local arrays. R8 disproved the union theory: WRITE_SIZE
// still ~175 MB, VGPR still 52. But 52 VGPR cannot hold the ~85 live values
// (wb 12, wfc 16, pf 16, offsets 23, acc 16, ptrs) -> the R7-added arrays
// (pf[4] + 6 offset arrays) are sitting in scratch as unpromoted allocas:
// pf alone = 64 B/lane/iter = 268 MB stores/dispatch, ~65% written back =
// the measured 175 MB. Worse: storing pf to scratch forces vmcnt(0) right
// after the prefetch loads -> HBM latency back ON the critical path,
// defeating R7's prefetch. Fix: no arrays anywhere. pf0..pf3, named offset
// ints (statement-expr init), wfc as 4 named f32x4, wb0..2, acc0..3,
// make_uint4 rvalue store. Nothing left to alloca.
// Predicted: WRITE -> <=2 MB, VGPR -> 85-110, dur 160 -> 110-145.

typedef short bf16x8 __attribute__((ext_vector_type(8)));
typedef float f32x4  __attribute__((ext_vector_type(4)));

#define NBLOCKS 4096
#define Z1_RS 19                    // z1 row stride in 16B slots (odd!)
#define Z1_SLOTS (15 * Z1_RS)       // 285 slots per image
#define IMG_RS 36                   // simg row stride in floats (16B-aligned rows)
#define IMG_ROWS 29                 // rows -1..27 stored at ro = r+1
#define IMG_FLOATS (IMG_ROWS * IMG_RS)   // 1044 floats = 4176 B

static __device__ __forceinline__ short f2bf(float f) {
    union { float f; unsigned u; } v; v.f = f;
    unsigned r = v.u + 0x7FFF + ((v.u >> 16) & 1);   // RNE (no NaN inputs)
    return (short)(r >> 16);
}

// One conv1 channel pair (CA, CA+1): 9-tap FMA + ReLU + pack to 2xbf16.
#define CONV1_PAIR(CA, PKDST) do {                                          \
    const float* wa_ = &W1[(CA) * 9];                                       \
    const float* wc_ = &W1[((CA) + 1) * 9];                                 \
    float za_ = b1[(CA)], zc_ = b1[(CA) + 1];                               \
    za_ = fmaf(t0, wa_[0], za_); zc_ = fmaf(t0, wc_[0], zc_);               \
    za_ = fmaf(t1, wa_[1], za_); zc_ = fmaf(t1, wc_[1], zc_);               \
    za_ = fmaf(t2, wa_[2], za_); zc_ = fmaf(t2, wc_[2], zc_);               \
    za_ = fmaf(t3, wa_[3], za_); zc_ = fmaf(t3, wc_[3], zc_);               \
    za_ = fmaf(t4, wa_[4], za_); zc_ = fmaf(t4, wc_[4], zc_);               \
    za_ = fmaf(t5, wa_[5], za_); zc_ = fmaf(t5, wc_[5], zc_);               \
    za_ = fmaf(t6, wa_[6], za_); zc_ = fmaf(t6, wc_[6], zc_);               \
    za_ = fmaf(t7, wa_[7], za_); zc_ = fmaf(t7, wc_[7], zc_);               \
    za_ = fmaf(t8, wa_[8], za_); zc_ = fmaf(t8, wc_[8], zc_);               \
    za_ = fmaxf(za_, 0.f);       zc_ = fmaxf(zc_, 0.f);                     \
    asm("v_cvt_pk_bf16_f32 %0, %1, %2" : "=v"(PKDST) : "v"(za_), "v"(zc_)); \
} while (0)

// One conv1 output position: 9 LDS taps -> 8 channels -> one 16B z1 store.
#define CONV1_STEP(WBOFF, ZOFF, STORE_COND) do {                              \
    const float* wbse = sw + (WBOFF);                                         \
    float t0 = wbse[0],            t1 = wbse[1],              t2 = wbse[2];   \
    float t3 = wbse[IMG_RS],       t4 = wbse[IMG_RS + 1],     t5 = wbse[IMG_RS + 2]; \
    float t6 = wbse[2 * IMG_RS],   t7 = wbse[2 * IMG_RS + 1], t8 = wbse[2 * IMG_RS + 2]; \
    asm volatile("" : "+v"(t0), "+v"(t1), "+v"(t2), "+v"(t3), "+v"(t4),      \
                      "+v"(t5), "+v"(t6), "+v"(t7), "+v"(t8));                \
    unsigned pk0_, pk1_, pk2_, pk3_;                                          \
    CONV1_PAIR(0, pk0_);                                                      \
    CONV1_PAIR(2, pk1_);                                                      \
    CONV1_PAIR(4, pk2_);                                                      \
    CONV1_PAIR(6, pk3_);                                                      \
    if (STORE_COND)                                                           \
        *(uint4*)(z1b + (ZOFF)) = make_uint4(pk0_, pk1_, pk2_, pk3_);         \
} while (0)

__global__ __launch_bounds__(256, 4) void fused_cnn_mfma(
    const float* __restrict__ x,
    const float* __restrict__ W1, const float* __restrict__ b1,
    const float* __restrict__ W2, const float* __restrict__ b2,
    const float* __restrict__ Wfc, const float* __restrict__ bfc,
    float* __restrict__ out, int nimg)
{
    __shared__ __align__(16) float simg[4][IMG_FLOATS];   // 16704 B
    __shared__ bf16x8 sz1[4][Z1_SLOTS];                   // 18240 B

    const int tid  = threadIdx.x;
    const int w    = tid >> 6;       // wave id = image slot (wave-private LDS)
    const int lane = tid & 63;
    const int hi   = lane >> 4;
    const int lo   = lane & 15;

    // ---------------- one-time setup (all wave-private, no barrier) --------
    {
        f32x4 z4 = {0.f, 0.f, 0.f, 0.f};
        f32x4* sp = (f32x4*)&simg[w][0];
        for (int i = lane; i < IMG_FLOATS / 4; i += 64) sp[i] = z4;
        bf16x8 zz = {0,0,0,0,0,0,0,0};
        for (int i = lane; i < Z1_SLOTS; i += 64) sz1[w][i] = zz;
    }

    // B-frags: W2 as bf16, named regs. k = tap*8 + ic; lane(hi,lo):
    // B[k=kk*32+hi*8+j][n=lo] -> tap = kk*4+hi, ic=j. tap>=9 => 0 (K-pad).
    #define MK_WB(KK) ({                                                    \
        bf16x8 v_;                                                          \
        const int tap_ = (KK) * 4 + hi;                                     \
        _Pragma("unroll")                                                   \
        for (int j = 0; j < 8; j++)                                         \
            v_[j] = (tap_ < 9) ? f2bf(W2[lo * 72 + j * 9 + tap_])           \
                               : (short)0;                                  \
        v_; })
    const bf16x8 wb0 = MK_WB(0), wb1 = MK_WB(1), wb2 = MK_WB(2);

    // conv2 A-read byte offsets into sz1[w]: slot = (2qy+ty)*19 + (2qx+tx)
    #define MK_POSOFF(T) ({                                                 \
        int p_ = (T) * 16 + lo; if (p_ > 48) p_ = 48;                       \
        int qy_ = p_ / 7, qx_ = p_ - qy_ * 7;                               \
        ((2 * qy_) * Z1_RS + 2 * qx_) * 16; })
    const int posoff0 = MK_POSOFF(0), posoff1 = MK_POSOFF(1),
              posoff2 = MK_POSOFF(2), posoff3 = MK_POSOFF(3);
    #define MK_TAPOFF(KK) ({                                                \
        int tap_ = (KK) * 4 + hi;                                           \
        int ty_ = tap_ / 3, tx_ = tap_ - ty_ * 3;                           \
        (tap_ < 9) ? (ty_ * Z1_RS + tx_) * 16 : 0; })
    const int tapoff0 = MK_TAPOFF(0), tapoff1 = MK_TAPOFF(1),
              tapoff2 = MK_TAPOFF(2);

    // Staging constants: float4 index in image + dst float offset.
    #define MK_SRC4(J) ({ int p4_ = (J) * 64 + lane;                        \
                          if (p4_ > 195) p4_ = 195; p4_; })
    const int src40 = MK_SRC4(0), src41 = MK_SRC4(1),
              src42 = MK_SRC4(2), src43 = MK_SRC4(3);
    #define MK_DSTF(J) ({                                                   \
        int p4_ = (J) * 64 + lane; if (p4_ > 195) p4_ = 195;                \
        int yy_ = p4_ / 7, xq_ = p4_ - yy_ * 7;                             \
        (yy_ + 1) * IMG_RS + 4 + 4 * xq_; })
    const int dstf0 = MK_DSTF(0), dstf1 = MK_DSTF(1),
              dstf2 = MK_DSTF(2), dstf3 = MK_DSTF(3);

    // conv1 constants: read base offset + z1 write byte offset.
    #define MK_WBOFF(I) ({                                                  \
        int p_ = (I) * 64 + lane; if (p_ > 195) p_ = 195;                   \
        int py_ = p_ / 14, px_ = p_ - py_ * 14;                             \
        (2 * py_) * IMG_RS + 2 * px_ + 3; })
    const int wboff0 = MK_WBOFF(0), wboff1 = MK_WBOFF(1),
              wboff2 = MK_WBOFF(2), wboff3 = MK_WBOFF(3);
    #define MK_ZOFF(I) ({                                                   \
        int p_ = (I) * 64 + lane; if (p_ > 195) p_ = 195;                   \
        int py_ = p_ / 14, px_ = p_ - py_ * 14;                             \
        ((py_ + 1) * Z1_RS + px_ + 1) * 16; })
    const int zoff0 = MK_ZOFF(0), zoff1 = MK_ZOFF(1),
              zoff2 = MK_ZOFF(2), zoff3 = MK_ZOFF(3);

    // Epilogue constants: lane(hi,lo) holds D[pos=t*16+hi*4+r][c2=lo].
    const float b2v = b2[lo];
    #define MK_WFC(T) ({                                                    \
        f32x4 v_;                                                           \
        _Pragma("unroll")                                                   \
        for (int r = 0; r < 4; r++) {                                       \
            int p_ = (T) * 16 + hi * 4 + r;                                 \
            v_[r] = (p_ < 49) ? Wfc[lo * 49 + p_] : 0.f;                    \
        }                                                                   \
        v_; })
    const f32x4 wfct0 = MK_WFC(0), wfct1 = MK_WFC(1),
                wfct2 = MK_WFC(2), wfct3 = MK_WFC(3);
    const float bfc0 = bfc[0];

    const int nquad = (nimg + 3) >> 2;
    float* const sw = &simg[w][0];
    char* const z1b = (char*)&sz1[w][0];

    // ---- prologue prefetch: image for q = blockIdx.x ----
    float4 pf0, pf1, pf2, pf3;
    {
        int img = blockIdx.x * 4 + w;
        if (img >= nimg) img = nimg - 1;
        const float4* sp = (const float4*)(x + (size_t)img * 784);
        pf0 = sp[src40]; pf1 = sp[src41]; pf2 = sp[src42]; pf3 = sp[src43];
    }

    for (int q = blockIdx.x; q < nquad; q += gridDim.x) {
        // ---- write prefetched image to LDS (wave-private, aligned b128) ----
        *(float4*)(sw + dstf0) = pf0;
        *(float4*)(sw + dstf1) = pf1;
        *(float4*)(sw + dstf2) = pf2;
        if (lane < 4) *(float4*)(sw + dstf3) = pf3;

        // ---- issue next image's loads; they complete under conv1+conv2 ----
        {
            int qn = q + gridDim.x;
            if (qn < nquad) {
                int imgn = qn * 4 + w;
                if (imgn >= nimg) imgn = nimg - 1;
                const float4* sp = (const float4*)(x + (size_t)imgn * 784);
                pf0 = sp[src40]; pf1 = sp[src41];
                pf2 = sp[src42]; pf3 = sp[src43];
            }
        }

        // ---- conv1 (fp32 VALU); pack via v_cvt_pk_bf16_f32, SSA only ----
        CONV1_STEP(wboff0, zoff0, 1);
        CONV1_STEP(wboff1, zoff1, 1);
        CONV1_STEP(wboff2, zoff2, 1);
        CONV1_STEP(wboff3, zoff3, lane < 4);

        // ---- conv2: 4 pos-tiles x 3 K-steps; A = z1 (one b128/frag) ----
        f32x4 acc0 = {0.f, 0.f, 0.f, 0.f};
        f32x4 acc1 = {0.f, 0.f, 0.f, 0.f};
        f32x4 acc2 = {0.f, 0.f, 0.f, 0.f};
        f32x4 acc3 = {0.f, 0.f, 0.f, 0.f};
        #define C2(ACC, POS) do {                                           \
            ACC = __builtin_amdgcn_mfma_f32_16x16x32_bf16(                  \
                *(const bf16x8*)(z1b + (POS) + tapoff0), wb0, ACC, 0, 0, 0);\
            ACC = __builtin_amdgcn_mfma_f32_16x16x32_bf16(                  \
                *(const bf16x8*)(z1b + (POS) + tapoff1), wb1, ACC, 0, 0, 0);\
            ACC = __builtin_amdgcn_mfma_f32_16x16x32_bf16(                  \
                *(const bf16x8*)(z1b + (POS) + tapoff2), wb2, ACC, 0, 0, 0);\
        } while (0)
        C2(acc0, posoff0);
        C2(acc1, posoff1);
        C2(acc2, posoff2);
        C2(acc3, posoff3);

        // ---- epilogue: bias+ReLU+FC fold, wave reduce, softplus ----
        float fc = 0.f;
        #define EPI(ACC, WF) do {                                           \
            _Pragma("unroll")                                               \
            for (int r = 0; r < 4; r++) {                                   \
                float z_ = fmaxf((ACC)[r] + b2v, 0.f);                      \
                fc = fmaf(z_, (WF)[r], fc);                                 \
            }                                                               \
        } while (0)
        EPI(acc0, wfct0);
        EPI(acc1, wfct1);
        EPI(acc2, wfct2);
        EPI(acc3, wfct3);
        #pragma unroll
        for (int off = 32; off > 0; off >>= 1)
            fc += __shfl_down(fc, off, 64);

        if (lane == 0) {
            int img = q * 4 + w;
            if (img < nimg) {
                float v    = fc + bfc0;
                float sp   = fmaxf(v, 0.f) + log1pf(expf(-fabsf(v)));
                float rate = sp + 0.001f;
                float pr   = 1.f - expf(-rate);
                out[img] = fminf(fmaxf(pr, 1e-6f), 1.f - 1e-6f);
            }
        }
    }
}

extern "C" void kernel_launch(void* const* d_in, const int* in_sizes, int n_in,
                              void* d_out, int out_size, void* d_ws, size_t ws_size,
                              hipStream_t stream) {
    const float* x   = (const float*)d_in[0];
    const float* W1  = (const float*)d_in[1];
    const float* b1  = (const float*)d_in[2];
    const float* W2  = (const float*)d_in[3];
    const float* b2  = (const float*)d_in[4];
    const float* Wfc = (const float*)d_in[5];
    const float* bfc = (const float*)d_in[6];
    float* out = (float*)d_out;

    const int nimg  = in_sizes[0] / 784;
    const int nquad = (nimg + 3) / 4;
    const int grid  = nquad < NBLOCKS ? nquad : NBLOCKS;

    fused_cnn_mfma<<<grid, 256, 0, stream>>>(x, W1, b1, W2, b2, Wfc, bfc,
                                             out, nimg);
}